// Round 2
// baseline (685.492 us; speedup 1.0000x reference)
//
#include <hip/hip_runtime.h>
#include <hip/hip_bf16.h>

#define NNODES 32768
#define DEG 16

__device__ __forceinline__ float sigmoidf_(float x) { return 1.f / (1.f + __expf(-x)); }
__device__ __forceinline__ float tanhf_(float x) { return 1.f - 2.f / (__expf(2.f * x) + 1.f); }

// ---------------------------------------------------------------------------
// Generic tiled fp32 FC: out[N][FO] = in[N][FI] @ W + bias.
// W given row-major [FI][FO] (TRANSW=false) or as [FO][FI] to be used
// transposed (TRANSW=true, for x @ wih.T).
// Block 256 threads, 32 rows/block, column tile FOT (grid.y = FO/FOT).
// ---------------------------------------------------------------------------
template <int FI, int FO, int FOT, bool TRANSW>
__global__ __launch_bounds__(256) void fc_kernel(const float* __restrict__ in,
                                                 const float* __restrict__ W,
                                                 const float* __restrict__ bias,
                                                 float* __restrict__ out) {
  constexpr int ROWS = 32;
  constexpr int RIF = 256 / FOT;   // rows in flight
  constexpr int RP = ROWS / RIF;   // row iters per thread
  constexpr int PFI = (FI + 4) & ~3;  // padded leading dim (bank spread + 16B align)
  __shared__ float w_s[FI * FOT];
  __shared__ float in_s[ROWS * PFI];
  __shared__ float b_s[FOT];
  const int t = threadIdx.x;
  const int rowBase = blockIdx.x * ROWS;
  const int colBase = blockIdx.y * FOT;
  for (int idx = t; idx < FI * FOT; idx += 256) {
    int k = idx / FOT, jj = idx - k * FOT;
    w_s[idx] = TRANSW ? W[(size_t)(colBase + jj) * FI + k] : W[(size_t)k * FO + colBase + jj];
  }
  if (t < FOT) b_s[t] = bias[colBase + t];
  for (int idx = t; idx < ROWS * FI; idx += 256) {
    int r = idx / FI, k = idx - r * FI;
    in_s[r * PFI + k] = in[(size_t)(rowBase + r) * FI + k];
  }
  __syncthreads();
  const int jj = t % FOT;
  const int rslot = t / FOT;
#pragma unroll
  for (int rb = 0; rb < RP; rb += 4) {
    float acc0 = b_s[jj], acc1 = b_s[jj], acc2 = b_s[jj], acc3 = b_s[jj];
    const float* ip0 = &in_s[((rb + 0) * RIF + rslot) * PFI];
    const float* ip1 = &in_s[((rb + 1) * RIF + rslot) * PFI];
    const float* ip2 = &in_s[((rb + 2) * RIF + rslot) * PFI];
    const float* ip3 = &in_s[((rb + 3) * RIF + rslot) * PFI];
#pragma unroll 8
    for (int k = 0; k < FI; k++) {
      float wv = w_s[k * FOT + jj];
      acc0 += ip0[k] * wv;
      acc1 += ip1[k] * wv;
      acc2 += ip2[k] * wv;
      acc3 += ip3[k] * wv;
    }
    out[(size_t)(rowBase + (rb + 0) * RIF + rslot) * FO + colBase + jj] = acc0;
    out[(size_t)(rowBase + (rb + 1) * RIF + rslot) * FO + colBase + jj] = acc1;
    out[(size_t)(rowBase + (rb + 2) * RIF + rslot) * FO + colBase + jj] = acc2;
    out[(size_t)(rowBase + (rb + 3) * RIF + rslot) * FO + colBase + jj] = acc3;
  }
}

// ---------------------------------------------------------------------------
// GATv2 attention + epilogue.  H=4: F=128, one node per wave (head = lane>>4).
// H=1: F=32, 4 nodes per wave (node sub-id = lane>>4).  Each 16-lane group
// owns one (node, head): lane li holds features k = 2*li, 2*li+1.
// Online softmax over the 16 neighbors; out = acc/s + lin + bias (+ELU).
// ---------------------------------------------------------------------------
template <int H, bool ELU>
__global__ __launch_bounds__(256) void gat_kernel(const float* __restrict__ fs,
                                                  const float* __restrict__ fd,
                                                  const float* __restrict__ lin,
                                                  const int* __restrict__ src,
                                                  const float* __restrict__ attn,
                                                  const float* __restrict__ bias,
                                                  float* __restrict__ out) {
  constexpr int F = H * 32;
  const int lane = threadIdx.x & 63;
  const int wave = threadIdx.x >> 6;
  const int G = lane >> 4, li = lane & 15;
  int node, f0;
  if (H == 4) {
    node = blockIdx.x * 4 + wave;
    f0 = 2 * lane;
  } else {
    node = blockIdx.x * 16 + wave * 4 + G;
    f0 = 2 * li;
  }
  const int srcv = src[(size_t)node * DEG + li];
  const float2 fdv = *(const float2*)&fd[(size_t)node * F + f0];
  const float a0 = attn[f0];      // attn idx == feature idx for both H cases
  const float a1 = attn[f0 + 1];
  float m = -1e30f, s = 0.f, acc0 = 0.f, acc1 = 0.f;
  int sd = __shfl(srcv, (lane & 48), 64);
  float2 fsv = *(const float2*)&fs[(size_t)sd * F + f0];
#pragma unroll
  for (int d = 0; d < DEG; d++) {
    float2 cur = fsv;
    if (d < DEG - 1) {
      int sn = __shfl(srcv, (lane & 48) | (d + 1), 64);
      fsv = *(const float2*)&fs[(size_t)sn * F + f0];
    }
    float e0 = cur.x + fdv.x; e0 = (e0 > 0.f) ? e0 : 0.2f * e0;
    float e1 = cur.y + fdv.y; e1 = (e1 > 0.f) ? e1 : 0.2f * e1;
    float p = e0 * a0 + e1 * a1;
    p += __shfl_xor(p, 1, 64);
    p += __shfl_xor(p, 2, 64);
    p += __shfl_xor(p, 4, 64);
    p += __shfl_xor(p, 8, 64);
    float nm = fmaxf(m, p);
    float ex = __expf(p - nm);
    float sc = __expf(m - nm);
    s = s * sc + ex;
    acc0 = acc0 * sc + ex * cur.x;
    acc1 = acc1 * sc + ex * cur.y;
    m = nm;
  }
  float inv = 1.f / s;
  float2 lv = *(const float2*)&lin[(size_t)node * F + f0];
  float o0 = acc0 * inv + lv.x + bias[f0];
  float o1 = acc1 * inv + lv.y + bias[f0 + 1];
  if (ELU) {
    o0 = (o0 > 0.f) ? o0 : __expf(o0) - 1.f;
    o1 = (o1 > 0.f) ? o1 : __expf(o1) - 1.f;
  }
  *(float2*)&out[(size_t)node * F + f0] = make_float2(o0, o1);
}

// ---------------------------------------------------------------------------
// SAGE-1 input projection: FW[n][20] = feat[n][5] @ wih.T + b   (thread/node)
// ---------------------------------------------------------------------------
__global__ __launch_bounds__(256) void fw1_kernel(const float* __restrict__ feat,
                                                  const float* __restrict__ wih,
                                                  const float* __restrict__ b,
                                                  float* __restrict__ out) {
  __shared__ float w_s[100];
  __shared__ float b_s[20];
  if (threadIdx.x < 100) w_s[threadIdx.x] = wih[threadIdx.x];
  if (threadIdx.x < 20) b_s[threadIdx.x] = b[threadIdx.x];
  __syncthreads();
  const int n = blockIdx.x * 256 + threadIdx.x;
  float f[5];
#pragma unroll
  for (int k = 0; k < 5; k++) f[k] = feat[(size_t)n * 5 + k];
#pragma unroll
  for (int j = 0; j < 20; j++) {
    float a = b_s[j];
#pragma unroll
    for (int k = 0; k < 5; k++) a += f[k] * w_s[j * 5 + k];
    out[(size_t)n * 20 + j] = a;
  }
}

// ---------------------------------------------------------------------------
// SAGE-1 LSTM (hidden=5), thread per node, gates = FW[src[n,d]] + h @ whh.T
// __launch_bounds__(256,4): ~55 live floats/thread (g[20]+p0..p4+h+c) —
// a 64-VGPR budget (8 waves/EU) would spill to scratch.
// ---------------------------------------------------------------------------
__global__ __launch_bounds__(256, 4) void lstm1_kernel(const float* __restrict__ FW,
                                                       const int* __restrict__ src,
                                                       const float* __restrict__ whh,
                                                       float* __restrict__ hn_out) {
  __shared__ float w_s[100];  // whh [20][5]
  if (threadIdx.x < 100) w_s[threadIdx.x] = whh[threadIdx.x];
  __syncthreads();
  const int n = blockIdx.x * 256 + threadIdx.x;
  const int* sp = src + (size_t)n * DEG;
  float h[5] = {0, 0, 0, 0, 0}, c[5] = {0, 0, 0, 0, 0};
  int sd = sp[0];
  float4 p0 = *(const float4*)&FW[(size_t)sd * 20 + 0];
  float4 p1 = *(const float4*)&FW[(size_t)sd * 20 + 4];
  float4 p2 = *(const float4*)&FW[(size_t)sd * 20 + 8];
  float4 p3 = *(const float4*)&FW[(size_t)sd * 20 + 12];
  float4 p4 = *(const float4*)&FW[(size_t)sd * 20 + 16];
  for (int d = 0; d < DEG; d++) {
    float g[20];
    g[0] = p0.x; g[1] = p0.y; g[2] = p0.z; g[3] = p0.w;
    g[4] = p1.x; g[5] = p1.y; g[6] = p1.z; g[7] = p1.w;
    g[8] = p2.x; g[9] = p2.y; g[10] = p2.z; g[11] = p2.w;
    g[12] = p3.x; g[13] = p3.y; g[14] = p3.z; g[15] = p3.w;
    g[16] = p4.x; g[17] = p4.y; g[18] = p4.z; g[19] = p4.w;
    if (d < DEG - 1) {  // prefetch next neighbor's row
      int sn = sp[d + 1];
      p0 = *(const float4*)&FW[(size_t)sn * 20 + 0];
      p1 = *(const float4*)&FW[(size_t)sn * 20 + 4];
      p2 = *(const float4*)&FW[(size_t)sn * 20 + 8];
      p3 = *(const float4*)&FW[(size_t)sn * 20 + 12];
      p4 = *(const float4*)&FW[(size_t)sn * 20 + 16];
    }
#pragma unroll
    for (int j = 0; j < 20; j++) {
#pragma unroll
      for (int k = 0; k < 5; k++) g[j] += h[k] * w_s[j * 5 + k];
    }
#pragma unroll
    for (int k = 0; k < 5; k++) {
      float iv = sigmoidf_(g[k]);
      float fv = sigmoidf_(g[5 + k]);
      float gv = tanhf_(g[10 + k]);
      float ov = sigmoidf_(g[15 + k]);
      c[k] = fv * c[k] + iv * gv;
      h[k] = ov * tanhf_(c[k]);
    }
  }
#pragma unroll
  for (int k = 0; k < 5; k++) hn_out[(size_t)n * 5 + k] = h[k];
}

// ---------------------------------------------------------------------------
// SAGE-2 LSTM (hidden=32), one wave per node.
// Lane l owns gates j0=l (i/f half) and j1=l+64 (g/o half); whh rows live in
// 64 VGPRs; h broadcast via __shfl (readlane).  XW = x1 @ wih.T + b gathered
// per step.
// __launch_bounds__(256,4): 64 weight floats + ~35 live state needs ~110
// VGPRs. R1 profile showed VGPR_Count=60 (8-waves/EU budget) -> w0/w1
// spilled to scratch -> 105 MB HBM fetch + 208 us. 4 waves/EU = 128-VGPR
// budget, no spill.
// ---------------------------------------------------------------------------
__global__ __launch_bounds__(256, 4) void lstm2_kernel(const float* __restrict__ XW,
                                                       const int* __restrict__ src,
                                                       const float* __restrict__ whh,
                                                       float* __restrict__ hn_out) {
  const int lane = threadIdx.x & 63;
  const int wave = threadIdx.x >> 6;
  const int node = blockIdx.x * 4 + wave;
  float w0[32], w1[32];
#pragma unroll
  for (int k = 0; k < 32; k += 4) {
    float4 a = *(const float4*)&whh[(size_t)lane * 32 + k];
    w0[k] = a.x; w0[k + 1] = a.y; w0[k + 2] = a.z; w0[k + 3] = a.w;
    float4 b = *(const float4*)&whh[(size_t)(lane + 64) * 32 + k];
    w1[k] = b.x; w1[k + 1] = b.y; w1[k + 2] = b.z; w1[k + 3] = b.w;
  }
  const int srcv = src[(size_t)node * DEG + (lane & 15)];
  float c = 0.f, hprev = 0.f;
  int sd = __shfl(srcv, 0, 64);
  float xw0 = XW[(size_t)sd * 128 + lane];
  float xw1 = XW[(size_t)sd * 128 + 64 + lane];
#pragma unroll
  for (int d = 0; d < DEG; d++) {
    float g0 = xw0, g1 = xw1;
#pragma unroll
    for (int k = 0; k < 32; k++) {
      float hk = __shfl(hprev, k, 64);
      g0 += hk * w0[k];
      g1 += hk * w1[k];
    }
    if (d < DEG - 1) {
      int sn = __shfl(srcv, d + 1, 64);
      xw0 = XW[(size_t)sn * 128 + lane];
      xw1 = XW[(size_t)sn * 128 + 64 + lane];
    }
    // lanes<32: g0=i, g1=g(tanh); lanes>=32: g0=f, g1=o(sigmoid)
    float s0 = sigmoidf_(g0);
    float arg = (lane < 32) ? 2.f * g1 : g1;
    float sv = sigmoidf_(arg);
    float t1 = (lane < 32) ? (2.f * sv - 1.f) : sv;  // tanh(g) or sig(o)
    float f_ = __shfl_xor(s0, 32, 64);               // lanes<32 receive sig(f)
    float o_ = __shfl_xor(t1, 32, 64);               // lanes<32 receive sig(o)
    c = f_ * c + s0 * t1;
    hprev = o_ * tanhf_(c);  // valid on lanes<32; upper lanes garbage, never read
  }
  if (lane < 32) hn_out[(size_t)node * 32 + lane] = hprev;
}

// ---------------------------------------------------------------------------
// SAGE output: out = relu(in @ wself + hn @ wneigh + bias), FO=32
// ---------------------------------------------------------------------------
template <int FI>
__global__ __launch_bounds__(256) void sage_out_kernel(const float* __restrict__ in,
                                                       const float* __restrict__ hn,
                                                       const float* __restrict__ wself,
                                                       const float* __restrict__ wneigh,
                                                       const float* __restrict__ bias,
                                                       float* __restrict__ out) {
  __shared__ float ws_s[FI * 32];
  __shared__ float wn_s[FI * 32];
  __shared__ float b_s[32];
  for (int idx = threadIdx.x; idx < FI * 32; idx += 256) {
    ws_s[idx] = wself[idx];
    wn_s[idx] = wneigh[idx];
  }
  if (threadIdx.x < 32) b_s[threadIdx.x] = bias[threadIdx.x];
  __syncthreads();
  const int n = blockIdx.x * 8 + (threadIdx.x >> 5);
  const int j = threadIdx.x & 31;
  float a = b_s[j];
#pragma unroll
  for (int k = 0; k < FI; k++) a += in[(size_t)n * FI + k] * ws_s[k * 32 + j];
#pragma unroll
  for (int k = 0; k < FI; k++) a += hn[(size_t)n * FI + k] * wn_s[k * 32 + j];
  out[(size_t)n * 32 + j] = fmaxf(a, 0.f);
}

// ---------------------------------------------------------------------------
// Final MLP: out = relu([gat,x2] @ f1 + b1) @ f2 + b2   (thread per node)
// __launch_bounds__(256,4): z[64] live across the j-loop.
// ---------------------------------------------------------------------------
__global__ __launch_bounds__(256, 4) void final_kernel(const float* __restrict__ gat,
                                                       const float* __restrict__ x2,
                                                       const float* __restrict__ f1w,
                                                       const float* __restrict__ f1b,
                                                       const float* __restrict__ f2w,
                                                       const float* __restrict__ f2b,
                                                       float* __restrict__ out) {
  __shared__ float w1_s[64 * 16];
  __shared__ float b1_s[16];
  __shared__ float w2_s[16];
  for (int idx = threadIdx.x; idx < 1024; idx += 256) w1_s[idx] = f1w[idx];
  if (threadIdx.x < 16) {
    b1_s[threadIdx.x] = f1b[threadIdx.x];
    w2_s[threadIdx.x] = f2w[threadIdx.x];
  }
  __syncthreads();
  const int n = blockIdx.x * 256 + threadIdx.x;
  float z[64];
#pragma unroll
  for (int k = 0; k < 32; k += 4) {
    float4 a = *(const float4*)&gat[(size_t)n * 32 + k];
    z[k] = a.x; z[k + 1] = a.y; z[k + 2] = a.z; z[k + 3] = a.w;
    float4 b = *(const float4*)&x2[(size_t)n * 32 + k];
    z[32 + k] = b.x; z[32 + k + 1] = b.y; z[32 + k + 2] = b.z; z[32 + k + 3] = b.w;
  }
  float o = f2b[0];
#pragma unroll
  for (int j = 0; j < 16; j++) {
    float a = b1_s[j];
#pragma unroll
    for (int k = 0; k < 64; k++) a += z[k] * w1_s[k * 16 + j];
    o += fmaxf(a, 0.f) * w2_s[j];
  }
  out[n] = o;
}

extern "C" void kernel_launch(void* const* d_in, const int* in_sizes, int n_in,
                              void* d_out, int out_size, void* d_ws, size_t ws_size,
                              hipStream_t stream) {
  const int N = NNODES;
  const float* feat = (const float*)d_in[0];
  const int* src = (const int*)d_in[1];
  const float* g0_ws = (const float*)d_in[2];
  const float* g0_bs = (const float*)d_in[3];
  const float* g0_wd = (const float*)d_in[4];
  const float* g0_bd = (const float*)d_in[5];
  const float* g0_attn = (const float*)d_in[6];
  const float* g0_bias = (const float*)d_in[7];
  const float* l0_w = (const float*)d_in[8];
  const float* l0_b = (const float*)d_in[9];
  const float* g1_ws = (const float*)d_in[10];
  const float* g1_bs = (const float*)d_in[11];
  const float* g1_wd = (const float*)d_in[12];
  const float* g1_bd = (const float*)d_in[13];
  const float* g1_attn = (const float*)d_in[14];
  const float* g1_bias = (const float*)d_in[15];
  const float* l1_w = (const float*)d_in[16];
  const float* l1_b = (const float*)d_in[17];
  const float* g2_ws = (const float*)d_in[18];
  const float* g2_bs = (const float*)d_in[19];
  const float* g2_wd = (const float*)d_in[20];
  const float* g2_bd = (const float*)d_in[21];
  const float* g2_attn = (const float*)d_in[22];
  const float* g2_bias = (const float*)d_in[23];
  const float* l2_w = (const float*)d_in[24];
  const float* l2_b = (const float*)d_in[25];
  const float* s1_wih = (const float*)d_in[26];
  const float* s1_whh = (const float*)d_in[27];
  const float* s1_b = (const float*)d_in[28];
  const float* s1_wself = (const float*)d_in[29];
  const float* s1_wneigh = (const float*)d_in[30];
  const float* s1_bias = (const float*)d_in[31];
  const float* s2_wih = (const float*)d_in[32];
  const float* s2_whh = (const float*)d_in[33];
  const float* s2_b = (const float*)d_in[34];
  const float* s2_wself = (const float*)d_in[35];
  const float* s2_wneigh = (const float*)d_in[36];
  const float* s2_bias = (const float*)d_in[37];
  const float* f1_w = (const float*)d_in[38];
  const float* f1_b = (const float*)d_in[39];
  const float* f2_w = (const float*)d_in[40];
  const float* f2_b = (const float*)d_in[41];

  float* A = (float*)d_ws;                // N*128
  float* B = A + (size_t)N * 128;         // N*128
  float* C = B + (size_t)N * 128;         // N*128
  float* D = C + (size_t)N * 128;         // N*128
  float* E = D + (size_t)N * 128;         // N*128   (total 84 MB)

  // ---- GAT layer 0 (fi=5, H=4) ----
  fc_kernel<5, 128, 64, false><<<dim3(N / 32, 2), 256, 0, stream>>>(feat, g0_ws, g0_bs, A);
  fc_kernel<5, 128, 64, false><<<dim3(N / 32, 2), 256, 0, stream>>>(feat, g0_wd, g0_bd, B);
  fc_kernel<5, 128, 64, false><<<dim3(N / 32, 2), 256, 0, stream>>>(feat, l0_w, l0_b, C);
  gat_kernel<4, true><<<N / 4, 256, 0, stream>>>(A, B, C, src, g0_attn, g0_bias, D);  // D = h1

  // ---- GAT layer 1 (fi=128, H=4) ----
  fc_kernel<128, 128, 64, false><<<dim3(N / 32, 2), 256, 0, stream>>>(D, g1_ws, g1_bs, A);
  fc_kernel<128, 128, 64, false><<<dim3(N / 32, 2), 256, 0, stream>>>(D, g1_wd, g1_bd, B);
  fc_kernel<128, 128, 64, false><<<dim3(N / 32, 2), 256, 0, stream>>>(D, l1_w, l1_b, C);
  gat_kernel<4, true><<<N / 4, 256, 0, stream>>>(A, B, C, src, g1_attn, g1_bias, E);  // E = h2

  // ---- GAT layer 2 (fi=128, H=1) ----
  fc_kernel<128, 32, 32, false><<<dim3(N / 32, 1), 256, 0, stream>>>(E, g2_ws, g2_bs, A);
  fc_kernel<128, 32, 32, false><<<dim3(N / 32, 1), 256, 0, stream>>>(E, g2_wd, g2_bd, B);
  fc_kernel<128, 32, 32, false><<<dim3(N / 32, 1), 256, 0, stream>>>(E, l2_w, l2_b, C);
  gat_kernel<1, false><<<N / 16, 256, 0, stream>>>(A, B, C, src, g2_attn, g2_bias, D);  // D = gat [N,32]

  // ---- SAGE layer 1 ----
  fw1_kernel<<<N / 256, 256, 0, stream>>>(feat, s1_wih, s1_b, A);                 // A = FW1 [N,20]
  lstm1_kernel<<<N / 256, 256, 0, stream>>>(A, src, s1_whh, B);                   // B = hn1 [N,5]
  sage_out_kernel<5><<<N / 8, 256, 0, stream>>>(feat, B, s1_wself, s1_wneigh, s1_bias, C);  // C = x1 [N,32]

  // ---- SAGE layer 2 ----
  fc_kernel<32, 128, 64, true><<<dim3(N / 32, 2), 256, 0, stream>>>(C, s2_wih, s2_b, A);  // A = XW2 [N,128]
  lstm2_kernel<<<N / 4, 256, 0, stream>>>(A, src, s2_whh, B);                     // B = hn2 [N,32]
  sage_out_kernel<32><<<N / 8, 256, 0, stream>>>(C, B, s2_wself, s2_wneigh, s2_bias, E);  // E = x2 [N,32]

  // ---- Final MLP ----
  final_kernel<<<N / 256, 256, 0, stream>>>(D, E, f1_w, f1_b, f2_w, f2_b, (float*)d_out);
}

// Round 3
// 644.193 us; speedup vs baseline: 1.0641x; 1.0641x over previous
//
#include <hip/hip_runtime.h>
#include <hip/hip_bf16.h>

#define NNODES 32768
#define DEG 16

__device__ __forceinline__ float sigmoidf_(float x) { return 1.f / (1.f + __expf(-x)); }
__device__ __forceinline__ float tanhf_(float x) { return 1.f - 2.f / (__expf(2.f * x) + 1.f); }

// ---------------------------------------------------------------------------
// Tiled fp32 FC: out[N][FO] = in[N][FI] @ W + bias.
// W row-major [FI][FO] (TRANSW=false) or [FO][FI] used transposed (TRANSW).
// Block 256 threads, 32 rows; grid.y tiles FO by FOT=min(FO,64).
// Thread owns 1 column x R rows. Inner loop per k4: 4 lane-contiguous w_s
// b32 reads (2-way, free) + R wave-uniform broadcast b128 ip reads + 4R FMA
// -> VALU-bound (old version was 5 LDS b32 per 4 FMA -> LDS-pipe-bound).
// ---------------------------------------------------------------------------
template <int FI, int FO, bool TRANSW>
__global__ __launch_bounds__(256) void fc_kernel(const float* __restrict__ in,
                                                 const float* __restrict__ W,
                                                 const float* __restrict__ bias,
                                                 float* __restrict__ out) {
  constexpr int ROWS = 32;
  constexpr int FOT = (FO < 64) ? FO : 64;
  constexpr int NJ = FOT;
  constexpr int RSL = 256 / NJ;
  constexpr int R = ROWS / RSL;
  constexpr int PFI = (FI + 4) & ~3;  // padded row (16B-multiple, bank spread)
  __shared__ float w_s[FI * FOT];
  __shared__ float in_s[ROWS * PFI];
  __shared__ float b_s[FOT];
  const int t = threadIdx.x;
  const int rowBase = blockIdx.x * ROWS;
  const int colBase = blockIdx.y * FOT;
  for (int idx = t; idx < FI * FOT; idx += 256) {
    int k = idx / FOT, jj = idx - k * FOT;
    w_s[idx] = TRANSW ? W[(size_t)(colBase + jj) * FI + k] : W[(size_t)k * FO + colBase + jj];
  }
  if (t < FOT) b_s[t] = bias[colBase + t];
  for (int idx = t; idx < ROWS * FI; idx += 256) {
    int r = idx / FI, k = idx - r * FI;
    in_s[r * PFI + k] = in[(size_t)(rowBase + r) * FI + k];
  }
  __syncthreads();
  const int jj = t % NJ;
  const int rslot = t / NJ;
  float acc[R];
#pragma unroll
  for (int r = 0; r < R; r++) acc[r] = b_s[jj];
  constexpr int K4 = FI / 4;
#pragma unroll
  for (int k4 = 0; k4 < K4; k4++) {
    float wv0 = w_s[(4 * k4 + 0) * FOT + jj];
    float wv1 = w_s[(4 * k4 + 1) * FOT + jj];
    float wv2 = w_s[(4 * k4 + 2) * FOT + jj];
    float wv3 = w_s[(4 * k4 + 3) * FOT + jj];
#pragma unroll
    for (int r = 0; r < R; r++) {
      float4 ip = *(const float4*)&in_s[(rslot * R + r) * PFI + 4 * k4];
      acc[r] += ip.x * wv0 + ip.y * wv1 + ip.z * wv2 + ip.w * wv3;
    }
  }
#pragma unroll
  for (int k = 4 * K4; k < FI; k++) {  // FI%4 remainder (FI=5)
    float wv = w_s[k * FOT + jj];
#pragma unroll
    for (int r = 0; r < R; r++) acc[r] += in_s[(rslot * R + r) * PFI + k] * wv;
  }
#pragma unroll
  for (int r = 0; r < R; r++)
    out[(size_t)(rowBase + rslot * R + r) * FO + colBase + jj] = acc[r];
}

// ---------------------------------------------------------------------------
// GATv2 attention + epilogue.  H=4: F=128, one node per wave (head = lane>>4).
// H=1: F=32, 4 nodes per wave.  16-lane group owns one (node, head); lane li
// holds features 2*li, 2*li+1. Online softmax over 16 neighbors.
// ---------------------------------------------------------------------------
template <int H, bool ELU>
__global__ __launch_bounds__(256) void gat_kernel(const float* __restrict__ fs,
                                                  const float* __restrict__ fd,
                                                  const float* __restrict__ lin,
                                                  const int* __restrict__ src,
                                                  const float* __restrict__ attn,
                                                  const float* __restrict__ bias,
                                                  float* __restrict__ out) {
  constexpr int F = H * 32;
  const int lane = threadIdx.x & 63;
  const int wave = threadIdx.x >> 6;
  const int G = lane >> 4, li = lane & 15;
  int node, f0;
  if (H == 4) {
    node = blockIdx.x * 4 + wave;
    f0 = 2 * lane;
  } else {
    node = blockIdx.x * 16 + wave * 4 + G;
    f0 = 2 * li;
  }
  const int srcv = src[(size_t)node * DEG + li];
  const float2 fdv = *(const float2*)&fd[(size_t)node * F + f0];
  const float a0 = attn[f0];
  const float a1 = attn[f0 + 1];
  float m = -1e30f, s = 0.f, acc0 = 0.f, acc1 = 0.f;
  int sd = __shfl(srcv, (lane & 48), 64);
  float2 fsv = *(const float2*)&fs[(size_t)sd * F + f0];
#pragma unroll
  for (int d = 0; d < DEG; d++) {
    float2 cur = fsv;
    if (d < DEG - 1) {
      int sn = __shfl(srcv, (lane & 48) | (d + 1), 64);
      fsv = *(const float2*)&fs[(size_t)sn * F + f0];
    }
    float e0 = cur.x + fdv.x; e0 = (e0 > 0.f) ? e0 : 0.2f * e0;
    float e1 = cur.y + fdv.y; e1 = (e1 > 0.f) ? e1 : 0.2f * e1;
    float p = e0 * a0 + e1 * a1;
    p += __shfl_xor(p, 1, 64);
    p += __shfl_xor(p, 2, 64);
    p += __shfl_xor(p, 4, 64);
    p += __shfl_xor(p, 8, 64);
    float nm = fmaxf(m, p);
    float ex = __expf(p - nm);
    float sc = __expf(m - nm);
    s = s * sc + ex;
    acc0 = acc0 * sc + ex * cur.x;
    acc1 = acc1 * sc + ex * cur.y;
    m = nm;
  }
  float inv = 1.f / s;
  float2 lv = *(const float2*)&lin[(size_t)node * F + f0];
  float o0 = acc0 * inv + lv.x + bias[f0];
  float o1 = acc1 * inv + lv.y + bias[f0 + 1];
  if (ELU) {
    o0 = (o0 > 0.f) ? o0 : __expf(o0) - 1.f;
    o1 = (o1 > 0.f) ? o1 : __expf(o1) - 1.f;
  }
  *(float2*)&out[(size_t)node * F + f0] = make_float2(o0, o1);
}

// ---------------------------------------------------------------------------
// SAGE-1 input projection: FW[n][20] = feat[n][5] @ wih.T + b   (thread/node)
// ---------------------------------------------------------------------------
__global__ __launch_bounds__(256) void fw1_kernel(const float* __restrict__ feat,
                                                  const float* __restrict__ wih,
                                                  const float* __restrict__ b,
                                                  float* __restrict__ out) {
  __shared__ float w_s[100];
  __shared__ float b_s[20];
  if (threadIdx.x < 100) w_s[threadIdx.x] = wih[threadIdx.x];
  if (threadIdx.x < 20) b_s[threadIdx.x] = b[threadIdx.x];
  __syncthreads();
  const int n = blockIdx.x * 256 + threadIdx.x;
  float f[5];
#pragma unroll
  for (int k = 0; k < 5; k++) f[k] = feat[(size_t)n * 5 + k];
#pragma unroll
  for (int j = 0; j < 20; j++) {
    float a = b_s[j];
#pragma unroll
    for (int k = 0; k < 5; k++) a += f[k] * w_s[j * 5 + k];
    out[(size_t)n * 20 + j] = a;
  }
}

// ---------------------------------------------------------------------------
// SAGE-1 LSTM (hidden=5), thread per node.
// ---------------------------------------------------------------------------
__global__ __launch_bounds__(256, 4) void lstm1_kernel(const float* __restrict__ FW,
                                                       const int* __restrict__ src,
                                                       const float* __restrict__ whh,
                                                       float* __restrict__ hn_out) {
  __shared__ float w_s[100];  // whh [20][5]
  if (threadIdx.x < 100) w_s[threadIdx.x] = whh[threadIdx.x];
  __syncthreads();
  const int n = blockIdx.x * 256 + threadIdx.x;
  const int* sp = src + (size_t)n * DEG;
  float h[5] = {0, 0, 0, 0, 0}, c[5] = {0, 0, 0, 0, 0};
  int sd = sp[0];
  float4 p0 = *(const float4*)&FW[(size_t)sd * 20 + 0];
  float4 p1 = *(const float4*)&FW[(size_t)sd * 20 + 4];
  float4 p2 = *(const float4*)&FW[(size_t)sd * 20 + 8];
  float4 p3 = *(const float4*)&FW[(size_t)sd * 20 + 12];
  float4 p4 = *(const float4*)&FW[(size_t)sd * 20 + 16];
  for (int d = 0; d < DEG; d++) {
    float g[20];
    g[0] = p0.x; g[1] = p0.y; g[2] = p0.z; g[3] = p0.w;
    g[4] = p1.x; g[5] = p1.y; g[6] = p1.z; g[7] = p1.w;
    g[8] = p2.x; g[9] = p2.y; g[10] = p2.z; g[11] = p2.w;
    g[12] = p3.x; g[13] = p3.y; g[14] = p3.z; g[15] = p3.w;
    g[16] = p4.x; g[17] = p4.y; g[18] = p4.z; g[19] = p4.w;
    if (d < DEG - 1) {
      int sn = sp[d + 1];
      p0 = *(const float4*)&FW[(size_t)sn * 20 + 0];
      p1 = *(const float4*)&FW[(size_t)sn * 20 + 4];
      p2 = *(const float4*)&FW[(size_t)sn * 20 + 8];
      p3 = *(const float4*)&FW[(size_t)sn * 20 + 12];
      p4 = *(const float4*)&FW[(size_t)sn * 20 + 16];
    }
#pragma unroll
    for (int j = 0; j < 20; j++) {
#pragma unroll
      for (int k = 0; k < 5; k++) g[j] += h[k] * w_s[j * 5 + k];
    }
#pragma unroll
    for (int k = 0; k < 5; k++) {
      float iv = sigmoidf_(g[k]);
      float fv = sigmoidf_(g[5 + k]);
      float gv = tanhf_(g[10 + k]);
      float ov = sigmoidf_(g[15 + k]);
      c[k] = fv * c[k] + iv * gv;
      h[k] = ov * tanhf_(c[k]);
    }
  }
#pragma unroll
  for (int k = 0; k < 5; k++) hn_out[(size_t)n * 5 + k] = h[k];
}

// ---------------------------------------------------------------------------
// SAGE-2 LSTM (hidden=32), one wave per node.
// Lane l owns gate rows l (i|f) and l+64 (g|o); the 64 whh floats live in
// VGPRs, protected from compiler rematerialization by an asm fence (R2
// post-mortem: const __restrict__ loads got re-loaded every step -> 10x VALU
// inflation at VGPR_Count=60; launch_bounds alone didn't help because remat
// is budget-independent).  h broadcast goes through LDS (write by lanes<32,
// re-read as 8 same-address b128 broadcasts) instead of 32 readlanes/step.
// ---------------------------------------------------------------------------
__global__ __launch_bounds__(256, 4) void lstm2_kernel(const float* __restrict__ XW,
                                                       const int* __restrict__ src,
                                                       const float* __restrict__ whh,
                                                       float* __restrict__ hn_out) {
  __shared__ float h_lds[4 * 36];
  const int lane = threadIdx.x & 63;
  const int wave = threadIdx.x >> 6;
  const int node = blockIdx.x * 4 + wave;
  float w0[32], w1[32];
#pragma unroll
  for (int k4 = 0; k4 < 8; k4++) {
    float4 a = *(const float4*)&whh[(size_t)lane * 32 + 4 * k4];
    float4 b = *(const float4*)&whh[(size_t)(lane + 64) * 32 + 4 * k4];
    w0[4 * k4 + 0] = a.x; w0[4 * k4 + 1] = a.y; w0[4 * k4 + 2] = a.z; w0[4 * k4 + 3] = a.w;
    w1[4 * k4 + 0] = b.x; w1[4 * k4 + 1] = b.y; w1[4 * k4 + 2] = b.z; w1[4 * k4 + 3] = b.w;
  }
#pragma unroll
  for (int k = 0; k < 32; k++) {  // remat fence: weights must stay in VGPRs
    asm volatile("" : "+v"(w0[k]));
    asm volatile("" : "+v"(w1[k]));
  }
  if (lane < 32) h_lds[wave * 36 + lane] = 0.f;
  const int* sp = src + (size_t)node * DEG;
  float c = 0.f, hprev = 0.f;
  int sd = sp[0];
  float xw0 = XW[(size_t)sd * 128 + lane];
  float xw1 = XW[(size_t)sd * 128 + 64 + lane];
#pragma unroll 1
  for (int d = 0; d < DEG; d++) {
    float g0 = xw0, g1 = xw1;
#pragma unroll
    for (int k4 = 0; k4 < 8; k4++) {
      float4 h4 = *(const float4*)&h_lds[wave * 36 + 4 * k4];  // broadcast
      g0 += h4.x * w0[4 * k4 + 0] + h4.y * w0[4 * k4 + 1] +
            h4.z * w0[4 * k4 + 2] + h4.w * w0[4 * k4 + 3];
      g1 += h4.x * w1[4 * k4 + 0] + h4.y * w1[4 * k4 + 1] +
            h4.z * w1[4 * k4 + 2] + h4.w * w1[4 * k4 + 3];
    }
    if (d < DEG - 1) {
      int sn = sp[d + 1];
      xw0 = XW[(size_t)sn * 128 + lane];
      xw1 = XW[(size_t)sn * 128 + 64 + lane];
    }
    // lanes<32: g0=i, g1=g(tanh); lanes>=32: g0=f, g1=o(sigmoid)
    float s0 = sigmoidf_(g0);
    float arg = (lane < 32) ? 2.f * g1 : g1;
    float sv = sigmoidf_(arg);
    float t1 = (lane < 32) ? (2.f * sv - 1.f) : sv;
    float f_ = __shfl_xor(s0, 32, 64);
    float o_ = __shfl_xor(t1, 32, 64);
    c = f_ * c + s0 * t1;
    hprev = o_ * tanhf_(c);  // valid on lanes<32
    if (lane < 32) h_lds[wave * 36 + lane] = hprev;
  }
  if (lane < 32) hn_out[(size_t)node * 32 + lane] = hprev;
}

// ---------------------------------------------------------------------------
// SAGE output: out = relu(in @ wself + hn @ wneigh + bias), FO=32
// ---------------------------------------------------------------------------
template <int FI>
__global__ __launch_bounds__(256) void sage_out_kernel(const float* __restrict__ in,
                                                       const float* __restrict__ hn,
                                                       const float* __restrict__ wself,
                                                       const float* __restrict__ wneigh,
                                                       const float* __restrict__ bias,
                                                       float* __restrict__ out) {
  __shared__ float ws_s[FI * 32];
  __shared__ float wn_s[FI * 32];
  __shared__ float b_s[32];
  for (int idx = threadIdx.x; idx < FI * 32; idx += 256) {
    ws_s[idx] = wself[idx];
    wn_s[idx] = wneigh[idx];
  }
  if (threadIdx.x < 32) b_s[threadIdx.x] = bias[threadIdx.x];
  __syncthreads();
  const int n = blockIdx.x * 8 + (threadIdx.x >> 5);
  const int j = threadIdx.x & 31;
  float a = b_s[j];
#pragma unroll
  for (int k = 0; k < FI; k++) a += in[(size_t)n * FI + k] * ws_s[k * 32 + j];
#pragma unroll
  for (int k = 0; k < FI; k++) a += hn[(size_t)n * FI + k] * wn_s[k * 32 + j];
  out[(size_t)n * 32 + j] = fmaxf(a, 0.f);
}

// ---------------------------------------------------------------------------
// Final MLP: out = relu([gat,x2] @ f1 + b1) @ f2 + b2   (thread per node)
// ---------------------------------------------------------------------------
__global__ __launch_bounds__(256, 4) void final_kernel(const float* __restrict__ gat,
                                                       const float* __restrict__ x2,
                                                       const float* __restrict__ f1w,
                                                       const float* __restrict__ f1b,
                                                       const float* __restrict__ f2w,
                                                       const float* __restrict__ f2b,
                                                       float* __restrict__ out) {
  __shared__ float w1_s[64 * 16];
  __shared__ float b1_s[16];
  __shared__ float w2_s[16];
  for (int idx = threadIdx.x; idx < 1024; idx += 256) w1_s[idx] = f1w[idx];
  if (threadIdx.x < 16) {
    b1_s[threadIdx.x] = f1b[threadIdx.x];
    w2_s[threadIdx.x] = f2w[threadIdx.x];
  }
  __syncthreads();
  const int n = blockIdx.x * 256 + threadIdx.x;
  float z[64];
#pragma unroll
  for (int k = 0; k < 32; k += 4) {
    float4 a = *(const float4*)&gat[(size_t)n * 32 + k];
    z[k] = a.x; z[k + 1] = a.y; z[k + 2] = a.z; z[k + 3] = a.w;
    float4 b = *(const float4*)&x2[(size_t)n * 32 + k];
    z[32 + k] = b.x; z[32 + k + 1] = b.y; z[32 + k + 2] = b.z; z[32 + k + 3] = b.w;
  }
  float o = f2b[0];
#pragma unroll
  for (int j = 0; j < 16; j++) {
    float a = b1_s[j];
#pragma unroll
    for (int k = 0; k < 64; k++) a += z[k] * w1_s[k * 16 + j];
    o += fmaxf(a, 0.f) * w2_s[j];
  }
  out[n] = o;
}

extern "C" void kernel_launch(void* const* d_in, const int* in_sizes, int n_in,
                              void* d_out, int out_size, void* d_ws, size_t ws_size,
                              hipStream_t stream) {
  const int N = NNODES;
  const float* feat = (const float*)d_in[0];
  const int* src = (const int*)d_in[1];
  const float* g0_ws = (const float*)d_in[2];
  const float* g0_bs = (const float*)d_in[3];
  const float* g0_wd = (const float*)d_in[4];
  const float* g0_bd = (const float*)d_in[5];
  const float* g0_attn = (const float*)d_in[6];
  const float* g0_bias = (const float*)d_in[7];
  const float* l0_w = (const float*)d_in[8];
  const float* l0_b = (const float*)d_in[9];
  const float* g1_ws = (const float*)d_in[10];
  const float* g1_bs = (const float*)d_in[11];
  const float* g1_wd = (const float*)d_in[12];
  const float* g1_bd = (const float*)d_in[13];
  const float* g1_attn = (const float*)d_in[14];
  const float* g1_bias = (const float*)d_in[15];
  const float* l1_w = (const float*)d_in[16];
  const float* l1_b = (const float*)d_in[17];
  const float* g2_ws = (const float*)d_in[18];
  const float* g2_bs = (const float*)d_in[19];
  const float* g2_wd = (const float*)d_in[20];
  const float* g2_bd = (const float*)d_in[21];
  const float* g2_attn = (const float*)d_in[22];
  const float* g2_bias = (const float*)d_in[23];
  const float* l2_w = (const float*)d_in[24];
  const float* l2_b = (const float*)d_in[25];
  const float* s1_wih = (const float*)d_in[26];
  const float* s1_whh = (const float*)d_in[27];
  const float* s1_b = (const float*)d_in[28];
  const float* s1_wself = (const float*)d_in[29];
  const float* s1_wneigh = (const float*)d_in[30];
  const float* s1_bias = (const float*)d_in[31];
  const float* s2_wih = (const float*)d_in[32];
  const float* s2_whh = (const float*)d_in[33];
  const float* s2_b = (const float*)d_in[34];
  const float* s2_wself = (const float*)d_in[35];
  const float* s2_wneigh = (const float*)d_in[36];
  const float* s2_bias = (const float*)d_in[37];
  const float* f1_w = (const float*)d_in[38];
  const float* f1_b = (const float*)d_in[39];
  const float* f2_w = (const float*)d_in[40];
  const float* f2_b = (const float*)d_in[41];

  float* A = (float*)d_ws;                // N*128
  float* B = A + (size_t)N * 128;         // N*128
  float* C = B + (size_t)N * 128;         // N*128
  float* D = C + (size_t)N * 128;         // N*128
  float* E = D + (size_t)N * 128;         // N*128   (total 84 MB)

  // ---- GAT layer 0 (fi=5, H=4) ----
  fc_kernel<5, 128, false><<<dim3(N / 32, 2), 256, 0, stream>>>(feat, g0_ws, g0_bs, A);
  fc_kernel<5, 128, false><<<dim3(N / 32, 2), 256, 0, stream>>>(feat, g0_wd, g0_bd, B);
  fc_kernel<5, 128, false><<<dim3(N / 32, 2), 256, 0, stream>>>(feat, l0_w, l0_b, C);
  gat_kernel<4, true><<<N / 4, 256, 0, stream>>>(A, B, C, src, g0_attn, g0_bias, D);  // D = h1

  // ---- GAT layer 1 (fi=128, H=4) ----
  fc_kernel<128, 128, false><<<dim3(N / 32, 2), 256, 0, stream>>>(D, g1_ws, g1_bs, A);
  fc_kernel<128, 128, false><<<dim3(N / 32, 2), 256, 0, stream>>>(D, g1_wd, g1_bd, B);
  fc_kernel<128, 128, false><<<dim3(N / 32, 2), 256, 0, stream>>>(D, l1_w, l1_b, C);
  gat_kernel<4, true><<<N / 4, 256, 0, stream>>>(A, B, C, src, g1_attn, g1_bias, E);  // E = h2

  // ---- GAT layer 2 (fi=128, H=1) ----
  fc_kernel<128, 32, false><<<dim3(N / 32, 1), 256, 0, stream>>>(E, g2_ws, g2_bs, A);
  fc_kernel<128, 32, false><<<dim3(N / 32, 1), 256, 0, stream>>>(E, g2_wd, g2_bd, B);
  fc_kernel<128, 32, false><<<dim3(N / 32, 1), 256, 0, stream>>>(E, l2_w, l2_b, C);
  gat_kernel<1, false><<<N / 16, 256, 0, stream>>>(A, B, C, src, g2_attn, g2_bias, D);  // D = gat [N,32]

  // ---- SAGE layer 1 ----
  fw1_kernel<<<N / 256, 256, 0, stream>>>(feat, s1_wih, s1_b, A);                 // A = FW1 [N,20]
  lstm1_kernel<<<N / 256, 256, 0, stream>>>(A, src, s1_whh, B);                   // B = hn1 [N,5]
  sage_out_kernel<5><<<N / 8, 256, 0, stream>>>(feat, B, s1_wself, s1_wneigh, s1_bias, C);  // C = x1 [N,32]

  // ---- SAGE layer 2 ----
  fc_kernel<32, 128, true><<<dim3(N / 32, 2), 256, 0, stream>>>(C, s2_wih, s2_b, A);  // A = XW2 [N,128]
  lstm2_kernel<<<N / 4, 256, 0, stream>>>(A, src, s2_whh, B);                     // B = hn2 [N,32]
  sage_out_kernel<32><<<N / 8, 256, 0, stream>>>(C, B, s2_wself, s2_wneigh, s2_bias, E);  // E = x2 [N,32]

  // ---- Final MLP ----
  final_kernel<<<N / 256, 256, 0, stream>>>(D, E, f1_w, f1_b, f2_w, f2_b, (float*)d_out);
}

// Round 4
// 577.010 us; speedup vs baseline: 1.1880x; 1.1164x over previous
//
#include <hip/hip_runtime.h>
#include <hip/hip_bf16.h>

#define NNODES 32768
#define DEG 16

__device__ __forceinline__ float sigmoidf_(float x) { return 1.f / (1.f + __expf(-x)); }
__device__ __forceinline__ float tanhf_(float x) { return 1.f - 2.f / (__expf(2.f * x) + 1.f); }

// ---------------------------------------------------------------------------
// Fused triple FC (same input, three weight sets): out_z = in @ W_z + b_z.
// blockIdx.z in {0,1,2} selects (W,b,out). Body identical to R3 fc_kernel
// (absmax 0.0 verified). W row-major [FI][FO].
// ---------------------------------------------------------------------------
template <int FI, int FO>
__global__ __launch_bounds__(256) void fc3_kernel(
    const float* __restrict__ in,
    const float* __restrict__ W0, const float* __restrict__ B0, float* __restrict__ O0,
    const float* __restrict__ W1, const float* __restrict__ B1, float* __restrict__ O1,
    const float* __restrict__ W2, const float* __restrict__ B2, float* __restrict__ O2) {
  constexpr int ROWS = 32;
  constexpr int FOT = (FO < 64) ? FO : 64;
  constexpr int NJ = FOT;
  constexpr int RSL = 256 / NJ;
  constexpr int R = ROWS / RSL;
  constexpr int PFI = (FI + 4) & ~3;
  __shared__ float w_s[FI * FOT];
  __shared__ float in_s[ROWS * PFI];
  __shared__ float b_s[FOT];
  const float* W = (blockIdx.z == 0) ? W0 : (blockIdx.z == 1) ? W1 : W2;
  const float* bias = (blockIdx.z == 0) ? B0 : (blockIdx.z == 1) ? B1 : B2;
  float* out = (blockIdx.z == 0) ? O0 : (blockIdx.z == 1) ? O1 : O2;
  const int t = threadIdx.x;
  const int rowBase = blockIdx.x * ROWS;
  const int colBase = blockIdx.y * FOT;
  for (int idx = t; idx < FI * FOT; idx += 256) {
    int k = idx / FOT, jj = idx - k * FOT;
    w_s[idx] = W[(size_t)k * FO + colBase + jj];
  }
  if (t < FOT) b_s[t] = bias[colBase + t];
  for (int idx = t; idx < ROWS * FI; idx += 256) {
    int r = idx / FI, k = idx - r * FI;
    in_s[r * PFI + k] = in[(size_t)(rowBase + r) * FI + k];
  }
  __syncthreads();
  const int jj = t % NJ;
  const int rslot = t / NJ;
  float acc[R];
#pragma unroll
  for (int r = 0; r < R; r++) acc[r] = b_s[jj];
  constexpr int K4 = FI / 4;
#pragma unroll
  for (int k4 = 0; k4 < K4; k4++) {
    float wv0 = w_s[(4 * k4 + 0) * FOT + jj];
    float wv1 = w_s[(4 * k4 + 1) * FOT + jj];
    float wv2 = w_s[(4 * k4 + 2) * FOT + jj];
    float wv3 = w_s[(4 * k4 + 3) * FOT + jj];
#pragma unroll
    for (int r = 0; r < R; r++) {
      float4 ip = *(const float4*)&in_s[(rslot * R + r) * PFI + 4 * k4];
      acc[r] += ip.x * wv0 + ip.y * wv1 + ip.z * wv2 + ip.w * wv3;
    }
  }
#pragma unroll
  for (int k = 4 * K4; k < FI; k++) {
    float wv = w_s[k * FOT + jj];
#pragma unroll
    for (int r = 0; r < R; r++) acc[r] += in_s[(rslot * R + r) * PFI + k] * wv;
  }
#pragma unroll
  for (int r = 0; r < R; r++)
    out[(size_t)(rowBase + rslot * R + r) * FO + colBase + jj] = acc[r];
}

// ---------------------------------------------------------------------------
// Single FC for XW2 = x1 @ wih.T + b  (W given [FO][FI], used transposed)
// ---------------------------------------------------------------------------
template <int FI, int FO>
__global__ __launch_bounds__(256) void fct_kernel(const float* __restrict__ in,
                                                  const float* __restrict__ W,
                                                  const float* __restrict__ bias,
                                                  float* __restrict__ out) {
  constexpr int ROWS = 32;
  constexpr int FOT = (FO < 64) ? FO : 64;
  constexpr int NJ = FOT;
  constexpr int RSL = 256 / NJ;
  constexpr int R = ROWS / RSL;
  constexpr int PFI = (FI + 4) & ~3;
  __shared__ float w_s[FI * FOT];
  __shared__ float in_s[ROWS * PFI];
  __shared__ float b_s[FOT];
  const int t = threadIdx.x;
  const int rowBase = blockIdx.x * ROWS;
  const int colBase = blockIdx.y * FOT;
  for (int idx = t; idx < FI * FOT; idx += 256) {
    int k = idx / FOT, jj = idx - k * FOT;
    w_s[idx] = W[(size_t)(colBase + jj) * FI + k];
  }
  if (t < FOT) b_s[t] = bias[colBase + t];
  for (int idx = t; idx < ROWS * FI; idx += 256) {
    int r = idx / FI, k = idx - r * FI;
    in_s[r * PFI + k] = in[(size_t)(rowBase + r) * FI + k];
  }
  __syncthreads();
  const int jj = t % NJ;
  const int rslot = t / NJ;
  float acc[R];
#pragma unroll
  for (int r = 0; r < R; r++) acc[r] = b_s[jj];
  constexpr int K4 = FI / 4;
#pragma unroll
  for (int k4 = 0; k4 < K4; k4++) {
    float wv0 = w_s[(4 * k4 + 0) * FOT + jj];
    float wv1 = w_s[(4 * k4 + 1) * FOT + jj];
    float wv2 = w_s[(4 * k4 + 2) * FOT + jj];
    float wv3 = w_s[(4 * k4 + 3) * FOT + jj];
#pragma unroll
    for (int r = 0; r < R; r++) {
      float4 ip = *(const float4*)&in_s[(rslot * R + r) * PFI + 4 * k4];
      acc[r] += ip.x * wv0 + ip.y * wv1 + ip.z * wv2 + ip.w * wv3;
    }
  }
#pragma unroll
  for (int r = 0; r < R; r++)
    out[(size_t)(rowBase + rslot * R + r) * FO + colBase + jj] = acc[r];
}

// ---------------------------------------------------------------------------
// GATv2 attention + epilogue (unchanged from R3).
// ---------------------------------------------------------------------------
template <int H, bool ELU>
__global__ __launch_bounds__(256) void gat_kernel(const float* __restrict__ fs,
                                                  const float* __restrict__ fd,
                                                  const float* __restrict__ lin,
                                                  const int* __restrict__ src,
                                                  const float* __restrict__ attn,
                                                  const float* __restrict__ bias,
                                                  float* __restrict__ out) {
  constexpr int F = H * 32;
  const int lane = threadIdx.x & 63;
  const int wave = threadIdx.x >> 6;
  const int G = lane >> 4, li = lane & 15;
  int node, f0;
  if (H == 4) {
    node = blockIdx.x * 4 + wave;
    f0 = 2 * lane;
  } else {
    node = blockIdx.x * 16 + wave * 4 + G;
    f0 = 2 * li;
  }
  const int srcv = src[(size_t)node * DEG + li];
  const float2 fdv = *(const float2*)&fd[(size_t)node * F + f0];
  const float a0 = attn[f0];
  const float a1 = attn[f0 + 1];
  float m = -1e30f, s = 0.f, acc0 = 0.f, acc1 = 0.f;
  int sd = __shfl(srcv, (lane & 48), 64);
  float2 fsv = *(const float2*)&fs[(size_t)sd * F + f0];
#pragma unroll
  for (int d = 0; d < DEG; d++) {
    float2 cur = fsv;
    if (d < DEG - 1) {
      int sn = __shfl(srcv, (lane & 48) | (d + 1), 64);
      fsv = *(const float2*)&fs[(size_t)sn * F + f0];
    }
    float e0 = cur.x + fdv.x; e0 = (e0 > 0.f) ? e0 : 0.2f * e0;
    float e1 = cur.y + fdv.y; e1 = (e1 > 0.f) ? e1 : 0.2f * e1;
    float p = e0 * a0 + e1 * a1;
    p += __shfl_xor(p, 1, 64);
    p += __shfl_xor(p, 2, 64);
    p += __shfl_xor(p, 4, 64);
    p += __shfl_xor(p, 8, 64);
    float nm = fmaxf(m, p);
    float ex = __expf(p - nm);
    float sc = __expf(m - nm);
    s = s * sc + ex;
    acc0 = acc0 * sc + ex * cur.x;
    acc1 = acc1 * sc + ex * cur.y;
    m = nm;
  }
  float inv = 1.f / s;
  float2 lv = *(const float2*)&lin[(size_t)node * F + f0];
  float o0 = acc0 * inv + lv.x + bias[f0];
  float o1 = acc1 * inv + lv.y + bias[f0 + 1];
  if (ELU) {
    o0 = (o0 > 0.f) ? o0 : __expf(o0) - 1.f;
    o1 = (o1 > 0.f) ? o1 : __expf(o1) - 1.f;
  }
  *(float2*)&out[(size_t)node * F + f0] = make_float2(o0, o1);
}

// ---------------------------------------------------------------------------
// SAGE-1 input projection: FW[n][20] = feat[n][5] @ wih.T + b   (thread/node)
// ---------------------------------------------------------------------------
__global__ __launch_bounds__(256) void fw1_kernel(const float* __restrict__ feat,
                                                  const float* __restrict__ wih,
                                                  const float* __restrict__ b,
                                                  float* __restrict__ out) {
  __shared__ float w_s[100];
  __shared__ float b_s[20];
  if (threadIdx.x < 100) w_s[threadIdx.x] = wih[threadIdx.x];
  if (threadIdx.x < 20) b_s[threadIdx.x] = b[threadIdx.x];
  __syncthreads();
  const int n = blockIdx.x * 256 + threadIdx.x;
  float f[5];
#pragma unroll
  for (int k = 0; k < 5; k++) f[k] = feat[(size_t)n * 5 + k];
#pragma unroll
  for (int j = 0; j < 20; j++) {
    float a = b_s[j];
#pragma unroll
    for (int k = 0; k < 5; k++) a += f[k] * w_s[j * 5 + k];
    out[(size_t)n * 20 + j] = a;
  }
}

// ---------------------------------------------------------------------------
// SAGE-1: LSTM (hidden=5, thread/node) + fused output projection
// x1 = relu(feat @ wself + h @ wneigh + bias).
// amdgpu_waves_per_eu(1,4): allow up to 512 regs, target <=4 waves/EU so the
// allocator keeps g[20]+prefetch live instead of spilling (R3 lesson: the RA
// spills toward max occupancy unless the *max* waves target is lowered).
// ---------------------------------------------------------------------------
__global__ __attribute__((amdgpu_waves_per_eu(1, 4))) __launch_bounds__(256)
void lstm1s_kernel(const float* __restrict__ FW, const int* __restrict__ src,
                   const float* __restrict__ whh, const float* __restrict__ feat,
                   const float* __restrict__ wself, const float* __restrict__ wneigh,
                   const float* __restrict__ bias, float* __restrict__ x1out) {
  __shared__ float w_s[100];   // whh [20][5]
  __shared__ float ws_s[160];  // wself [5][32]
  __shared__ float wn_s[160];  // wneigh [5][32]
  __shared__ float b_s[32];
  if (threadIdx.x < 100) w_s[threadIdx.x] = whh[threadIdx.x];
  if (threadIdx.x < 160) {
    ws_s[threadIdx.x] = wself[threadIdx.x];
    wn_s[threadIdx.x] = wneigh[threadIdx.x];
  }
  if (threadIdx.x < 32) b_s[threadIdx.x] = bias[threadIdx.x];
  __syncthreads();
  const int n = blockIdx.x * 256 + threadIdx.x;
  const int* sp = src + (size_t)n * DEG;
  float f[5];
#pragma unroll
  for (int k = 0; k < 5; k++) f[k] = feat[(size_t)n * 5 + k];
  float h[5] = {0, 0, 0, 0, 0}, c[5] = {0, 0, 0, 0, 0};
  int sd = sp[0];
  float4 p0 = *(const float4*)&FW[(size_t)sd * 20 + 0];
  float4 p1 = *(const float4*)&FW[(size_t)sd * 20 + 4];
  float4 p2 = *(const float4*)&FW[(size_t)sd * 20 + 8];
  float4 p3 = *(const float4*)&FW[(size_t)sd * 20 + 12];
  float4 p4 = *(const float4*)&FW[(size_t)sd * 20 + 16];
  for (int d = 0; d < DEG; d++) {
    float g[20];
    g[0] = p0.x; g[1] = p0.y; g[2] = p0.z; g[3] = p0.w;
    g[4] = p1.x; g[5] = p1.y; g[6] = p1.z; g[7] = p1.w;
    g[8] = p2.x; g[9] = p2.y; g[10] = p2.z; g[11] = p2.w;
    g[12] = p3.x; g[13] = p3.y; g[14] = p3.z; g[15] = p3.w;
    g[16] = p4.x; g[17] = p4.y; g[18] = p4.z; g[19] = p4.w;
    if (d < DEG - 1) {
      int sn = sp[d + 1];
      p0 = *(const float4*)&FW[(size_t)sn * 20 + 0];
      p1 = *(const float4*)&FW[(size_t)sn * 20 + 4];
      p2 = *(const float4*)&FW[(size_t)sn * 20 + 8];
      p3 = *(const float4*)&FW[(size_t)sn * 20 + 12];
      p4 = *(const float4*)&FW[(size_t)sn * 20 + 16];
    }
#pragma unroll
    for (int j = 0; j < 20; j++) {
#pragma unroll
      for (int k = 0; k < 5; k++) g[j] += h[k] * w_s[j * 5 + k];
    }
#pragma unroll
    for (int k = 0; k < 5; k++) {
      float iv = sigmoidf_(g[k]);
      float fv = sigmoidf_(g[5 + k]);
      float gv = tanhf_(g[10 + k]);
      float ov = sigmoidf_(g[15 + k]);
      c[k] = fv * c[k] + iv * gv;
      h[k] = ov * tanhf_(c[k]);
    }
  }
  // fused SAGE-1 output projection
#pragma unroll
  for (int j = 0; j < 32; j++) {
    float a = b_s[j];
#pragma unroll
    for (int k = 0; k < 5; k++) a += f[k] * ws_s[k * 32 + j] + h[k] * wn_s[k * 32 + j];
    x1out[(size_t)n * 32 + j] = fmaxf(a, 0.f);
  }
}

// ---------------------------------------------------------------------------
// SAGE-2: LSTM (hidden=32, wave/node) + fused output projection.
// Lane l owns gate rows l (i|f) and l+64 (g|o); 64 whh floats in VGPRs.
// amdgpu_waves_per_eu(4,4): R3 post-mortem — launch_bounds(256,4) sets only a
// *minimum*; the RA still targeted 8 waves/EU (64-reg budget) and spilled all
// 64 fenced weights to scratch (VGPR_Count=60, 102MB fetch, 170us). Setting
// max=4 makes 128 regs the allocator's objective -> weights stay resident.
// ---------------------------------------------------------------------------
__global__ __attribute__((amdgpu_waves_per_eu(4, 4))) __launch_bounds__(256)
void lstm2s_kernel(const float* __restrict__ XW, const int* __restrict__ src,
                   const float* __restrict__ whh, const float* __restrict__ x1,
                   const float* __restrict__ wself, const float* __restrict__ wneigh,
                   const float* __restrict__ bias, float* __restrict__ x2out) {
  __shared__ float h_lds[4 * 36];
  __shared__ float x1_lds[4 * 32];
  __shared__ float sw_lds[2048];  // wself[1024] ++ wneigh[1024]
  const int t = threadIdx.x;
  const int lane = t & 63;
  const int wave = t >> 6;
  const int node = blockIdx.x * 4 + wave;
  for (int i = t; i < 1024; i += 256) {
    sw_lds[i] = wself[i];
    sw_lds[1024 + i] = wneigh[i];
  }
  float w0[32], w1[32];
#pragma unroll
  for (int k4 = 0; k4 < 8; k4++) {
    float4 a = *(const float4*)&whh[(size_t)lane * 32 + 4 * k4];
    float4 b = *(const float4*)&whh[(size_t)(lane + 64) * 32 + 4 * k4];
    w0[4 * k4 + 0] = a.x; w0[4 * k4 + 1] = a.y; w0[4 * k4 + 2] = a.z; w0[4 * k4 + 3] = a.w;
    w1[4 * k4 + 0] = b.x; w1[4 * k4 + 1] = b.y; w1[4 * k4 + 2] = b.z; w1[4 * k4 + 3] = b.w;
  }
#pragma unroll
  for (int k = 0; k < 32; k++) {  // remat fence: keep weights in VGPRs
    asm volatile("" : "+v"(w0[k]));
    asm volatile("" : "+v"(w1[k]));
  }
  if (lane < 32) h_lds[wave * 36 + lane] = 0.f;
  __syncthreads();  // sw_lds visibility (h_lds is same-wave only)
  const int* sp = src + (size_t)node * DEG;
  float c = 0.f, hprev = 0.f;
  int sd = sp[0];
  float xw0 = XW[(size_t)sd * 128 + lane];
  float xw1 = XW[(size_t)sd * 128 + 64 + lane];
#pragma unroll 1
  for (int d = 0; d < DEG; d++) {
    float g0 = xw0, g1 = xw1;
#pragma unroll
    for (int k4 = 0; k4 < 8; k4++) {
      float4 h4 = *(const float4*)&h_lds[wave * 36 + 4 * k4];  // broadcast
      g0 += h4.x * w0[4 * k4 + 0] + h4.y * w0[4 * k4 + 1] +
            h4.z * w0[4 * k4 + 2] + h4.w * w0[4 * k4 + 3];
      g1 += h4.x * w1[4 * k4 + 0] + h4.y * w1[4 * k4 + 1] +
            h4.z * w1[4 * k4 + 2] + h4.w * w1[4 * k4 + 3];
    }
    if (d < DEG - 1) {
      int sn = sp[d + 1];
      xw0 = XW[(size_t)sn * 128 + lane];
      xw1 = XW[(size_t)sn * 128 + 64 + lane];
    }
    // lanes<32: g0=i, g1=g(tanh); lanes>=32: g0=f, g1=o(sigmoid)
    float s0 = sigmoidf_(g0);
    float arg = (lane < 32) ? 2.f * g1 : g1;
    float sv = sigmoidf_(arg);
    float t1 = (lane < 32) ? (2.f * sv - 1.f) : sv;
    float f_ = __shfl_xor(s0, 32, 64);
    float o_ = __shfl_xor(t1, 32, 64);
    c = f_ * c + s0 * t1;
    hprev = o_ * tanhf_(c);  // valid on lanes<32
    if (lane < 32) h_lds[wave * 36 + lane] = hprev;
  }
  // fused SAGE-2 output: x2 = relu(x1 @ wself + hn @ wneigh + bias)
  if (lane < 32) x1_lds[wave * 32 + lane] = x1[(size_t)node * 32 + lane];
  if (lane < 32) {
    float a = bias[lane];
#pragma unroll
    for (int k = 0; k < 32; k++) {
      float xv = x1_lds[wave * 32 + k];  // broadcast
      float hv = h_lds[wave * 36 + k];   // broadcast (final h)
      a += xv * sw_lds[k * 32 + lane] + hv * sw_lds[1024 + k * 32 + lane];
    }
    x2out[(size_t)node * 32 + lane] = fmaxf(a, 0.f);
  }
}

// ---------------------------------------------------------------------------
// Final MLP: out = relu([gat,x2] @ f1 + b1) @ f2 + b2   (thread per node)
// waves_per_eu(4,4): z[64] live across the j-loop (same spill hazard).
// ---------------------------------------------------------------------------
__global__ __attribute__((amdgpu_waves_per_eu(4, 4))) __launch_bounds__(256)
void final_kernel(const float* __restrict__ gat,
                  const float* __restrict__ x2,
                  const float* __restrict__ f1w,
                  const float* __restrict__ f1b,
                  const float* __restrict__ f2w,
                  const float* __restrict__ f2b,
                  float* __restrict__ out) {
  __shared__ float w1_s[64 * 16];
  __shared__ float b1_s[16];
  __shared__ float w2_s[16];
  for (int idx = threadIdx.x; idx < 1024; idx += 256) w1_s[idx] = f1w[idx];
  if (threadIdx.x < 16) {
    b1_s[threadIdx.x] = f1b[threadIdx.x];
    w2_s[threadIdx.x] = f2w[threadIdx.x];
  }
  __syncthreads();
  const int n = blockIdx.x * 256 + threadIdx.x;
  float z[64];
#pragma unroll
  for (int k = 0; k < 32; k += 4) {
    float4 a = *(const float4*)&gat[(size_t)n * 32 + k];
    z[k] = a.x; z[k + 1] = a.y; z[k + 2] = a.z; z[k + 3] = a.w;
    float4 b = *(const float4*)&x2[(size_t)n * 32 + k];
    z[32 + k] = b.x; z[32 + k + 1] = b.y; z[32 + k + 2] = b.z; z[32 + k + 3] = b.w;
  }
  float o = f2b[0];
#pragma unroll
  for (int j = 0; j < 16; j++) {
    float a = b1_s[j];
#pragma unroll
    for (int k = 0; k < 64; k++) a += z[k] * w1_s[k * 16 + j];
    o += fmaxf(a, 0.f) * w2_s[j];
  }
  out[n] = o;
}

extern "C" void kernel_launch(void* const* d_in, const int* in_sizes, int n_in,
                              void* d_out, int out_size, void* d_ws, size_t ws_size,
                              hipStream_t stream) {
  const int N = NNODES;
  const float* feat = (const float*)d_in[0];
  const int* src = (const int*)d_in[1];
  const float* g0_ws = (const float*)d_in[2];
  const float* g0_bs = (const float*)d_in[3];
  const float* g0_wd = (const float*)d_in[4];
  const float* g0_bd = (const float*)d_in[5];
  const float* g0_attn = (const float*)d_in[6];
  const float* g0_bias = (const float*)d_in[7];
  const float* l0_w = (const float*)d_in[8];
  const float* l0_b = (const float*)d_in[9];
  const float* g1_ws = (const float*)d_in[10];
  const float* g1_bs = (const float*)d_in[11];
  const float* g1_wd = (const float*)d_in[12];
  const float* g1_bd = (const float*)d_in[13];
  const float* g1_attn = (const float*)d_in[14];
  const float* g1_bias = (const float*)d_in[15];
  const float* l1_w = (const float*)d_in[16];
  const float* l1_b = (const float*)d_in[17];
  const float* g2_ws = (const float*)d_in[18];
  const float* g2_bs = (const float*)d_in[19];
  const float* g2_wd = (const float*)d_in[20];
  const float* g2_bd = (const float*)d_in[21];
  const float* g2_attn = (const float*)d_in[22];
  const float* g2_bias = (const float*)d_in[23];
  const float* l2_w = (const float*)d_in[24];
  const float* l2_b = (const float*)d_in[25];
  const float* s1_wih = (const float*)d_in[26];
  const float* s1_whh = (const float*)d_in[27];
  const float* s1_b = (const float*)d_in[28];
  const float* s1_wself = (const float*)d_in[29];
  const float* s1_wneigh = (const float*)d_in[30];
  const float* s1_bias = (const float*)d_in[31];
  const float* s2_wih = (const float*)d_in[32];
  const float* s2_whh = (const float*)d_in[33];
  const float* s2_b = (const float*)d_in[34];
  const float* s2_wself = (const float*)d_in[35];
  const float* s2_wneigh = (const float*)d_in[36];
  const float* s2_bias = (const float*)d_in[37];
  const float* f1_w = (const float*)d_in[38];
  const float* f1_b = (const float*)d_in[39];
  const float* f2_w = (const float*)d_in[40];
  const float* f2_b = (const float*)d_in[41];

  float* A = (float*)d_ws;                // N*128
  float* B = A + (size_t)N * 128;
  float* C = B + (size_t)N * 128;
  float* D = C + (size_t)N * 128;
  float* E = D + (size_t)N * 128;         // total 84 MB

  // ---- GAT layer 0 (fi=5, H=4): fs->A fd->B lin->C ----
  fc3_kernel<5, 128><<<dim3(N / 32, 2, 3), 256, 0, stream>>>(
      feat, g0_ws, g0_bs, A, g0_wd, g0_bd, B, l0_w, l0_b, C);
  gat_kernel<4, true><<<N / 4, 256, 0, stream>>>(A, B, C, src, g0_attn, g0_bias, D);  // D = h1

  // ---- GAT layer 1 (fi=128, H=4) ----
  fc3_kernel<128, 128><<<dim3(N / 32, 2, 3), 256, 0, stream>>>(
      D, g1_ws, g1_bs, A, g1_wd, g1_bd, B, l1_w, l1_b, C);
  gat_kernel<4, true><<<N / 4, 256, 0, stream>>>(A, B, C, src, g1_attn, g1_bias, E);  // E = h2

  // ---- GAT layer 2 (fi=128, H=1) ----
  fc3_kernel<128, 32><<<dim3(N / 32, 1, 3), 256, 0, stream>>>(
      E, g2_ws, g2_bs, A, g2_wd, g2_bd, B, l2_w, l2_b, C);
  gat_kernel<1, false><<<N / 16, 256, 0, stream>>>(A, B, C, src, g2_attn, g2_bias, D);  // D = gat [N,32]

  // ---- SAGE layer 1 (E free after fc3 above) ----
  fw1_kernel<<<N / 256, 256, 0, stream>>>(feat, s1_wih, s1_b, E);  // E = FW1 [N,20]
  lstm1s_kernel<<<N / 256, 256, 0, stream>>>(E, src, s1_whh, feat, s1_wself,
                                             s1_wneigh, s1_bias, C);  // C = x1 [N,32]

  // ---- SAGE layer 2 ----
  fct_kernel<32, 128><<<dim3(N / 32, 2), 256, 0, stream>>>(C, s2_wih, s2_b, A);  // A = XW2
  lstm2s_kernel<<<N / 4, 256, 0, stream>>>(A, src, s2_whh, C, s2_wself,
                                           s2_wneigh, s2_bias, B);  // B = x2 [N,32]

  // ---- Final MLP ----
  final_kernel<<<N / 256, 256, 0, stream>>>(D, B, f1_w, f1_b, f2_w, f2_b, (float*)d_out);
}